// Round 9
// baseline (131.898 us; speedup 1.0000x reference)
//
#include <hip/hip_runtime.h>

#define T_STEPS 345
#define B_SZ    128
#define IN_SZ   13
#define H_SZ    128
#define OUT_SZ  9
#define XPITCH  16
#define NBO     (B_SZ * OUT_SZ)     // 1152
#define NCHUNK  22                  // 22*16 = 352 >= 345
#define TPADL   352                 // padded t extent inside LDS

// One block = one batch element; everything fused, intermediates in LDS.
//  phase 1 (waves 0-1): layer-1 mem1 scan -> spike ballot masks   [R8 k1 verbatim]
//  phase 2 (all waves): cur2[t][o] bit-masked dot                 [R8 k2 chain order]
//  phase 3 (lanes 0-8): mem2 scan, chunked, burst stores          [R8 k3 verbatim]
// ALL FP chains bit-identical to the passing R8 kernels (R3 lesson: knife-edge).
__global__ __launch_bounds__(384, 1)
void snn_fused(const float* __restrict__ x, const float* __restrict__ W1,
               const float* __restrict__ b1, const float* __restrict__ W2,
               const float* __restrict__ b2, const float* __restrict__ beta1p,
               const float* __restrict__ thr1p, const float* __restrict__ beta2p,
               const float* __restrict__ thr2p, float* __restrict__ out)
{
    const int b   = blockIdx.x;
    const int tid = threadIdx.x;    // 0..383

    __shared__ float xst[(T_STEPS + 3) * XPITCH];                     // 22,272 B
    __shared__ __align__(16) unsigned long long msk[T_STEPS][2];      //  5,520 B
    __shared__ float c2[TPADL * OUT_SZ];                              // 12,672 B

    // ---- stage + transpose x[b,:,:] (all 384 threads) ----
    const float* xb = x + (size_t)b * (IN_SZ * T_STEPS);
    for (int i = tid; i < IN_SZ * T_STEPS; i += 384) {
        const int c = i / T_STEPS;
        const int t = i - c * T_STEPS;
        xst[t * XPITCH + c] = xb[i];
    }
    __syncthreads();

    // =========== phase 1: layer-1 scan, threads 0..127 (waves 0-1) ===========
    if (tid < 128) {
        const float bt1 = fminf(fmaxf(beta1p[0], 0.0f), 1.0f);
        const float th1 = thr1p[0];

        float w1r[IN_SZ];
#pragma unroll
        for (int c = 0; c < IN_SZ; ++c) w1r[c] = W1[tid * IN_SZ + c];
        const float b1r = b1[tid];

        float mem1 = 0.0f;
        const int half = tid >> 6;
        const bool store_lane = (tid & 63) == 0;

        const float4* xq = (const float4*)xst;
        float4 a0 = xq[0], a1 = xq[1], a2 = xq[2]; float a3 = xst[12];
        float4 c0 = xq[4], c1 = xq[5], c2r = xq[6]; float c3 = xst[XPITCH + 12];

        int t = 0;
        for (; t < T_STEPS - 1; t += 2) {
            const float xa[IN_SZ] = { a0.x,a0.y,a0.z,a0.w, a1.x,a1.y,a1.z,a1.w,
                                      a2.x,a2.y,a2.z,a2.w, a3 };
            const float xc[IN_SZ] = { c0.x,c0.y,c0.z,c0.w, c1.x,c1.y,c1.z,c1.w,
                                      c2r.x,c2r.y,c2r.z,c2r.w, c3 };
            a0 = xq[(t+2)*4+0]; a1 = xq[(t+2)*4+1]; a2  = xq[(t+2)*4+2]; a3 = xst[(t+2)*XPITCH+12];
            c0 = xq[(t+3)*4+0]; c1 = xq[(t+3)*4+1]; c2r = xq[(t+3)*4+2]; c3 = xst[(t+3)*XPITCH+12];

            float cura = b1r, curb = b1r;
#pragma unroll
            for (int c = 0; c < IN_SZ; ++c) {
                cura = fmaf(xa[c], w1r[c], cura);
                curb = fmaf(xc[c], w1r[c], curb);
            }

            mem1 = fmaf(bt1, mem1, cura);
            const bool pa = mem1 > th1;
            const unsigned long long ma = __ballot(pa);
            mem1 = fmaf(pa ? -1.0f : 0.0f, th1, mem1);
            if (store_lane) msk[t][half] = ma;

            mem1 = fmaf(bt1, mem1, curb);
            const bool pb = mem1 > th1;
            const unsigned long long mb = __ballot(pb);
            mem1 = fmaf(pb ? -1.0f : 0.0f, th1, mem1);
            if (store_lane) msk[t + 1][half] = mb;
        }
        {   // tail t = 344
            const float xa[IN_SZ] = { a0.x,a0.y,a0.z,a0.w, a1.x,a1.y,a1.z,a1.w,
                                      a2.x,a2.y,a2.z,a2.w, a3 };
            float cura = b1r;
#pragma unroll
            for (int c = 0; c < IN_SZ; ++c) cura = fmaf(xa[c], w1r[c], cura);
            mem1 = fmaf(bt1, mem1, cura);
            const bool pa = mem1 > th1;
            const unsigned long long ma = __ballot(pa);
            if (store_lane) msk[t][half] = ma;
        }
    }
    __syncthreads();

    // =========== phase 2: cur2[t][o] from bit masks (lane = t) ===========
    if (tid < TPADL) {
        const int t  = tid;
        const int tc = (t < T_STEPS) ? t : (T_STEPS - 1);
        const uint4 mm = *(const uint4*)&msk[tc][0];

        float acc[OUT_SZ];
#pragma unroll
        for (int o = 0; o < OUT_SZ; ++o) acc[o] = 0.0f;

        // exact R8 k2 order: h = 0..127 via mm.x, mm.y, mm.z, mm.w
#pragma unroll
        for (int h = 0; h < 32; ++h) {
            const float bit = (float)((mm.x >> h) & 1u);
#pragma unroll
            for (int o = 0; o < OUT_SZ; ++o)
                acc[o] = fmaf(bit, W2[o * H_SZ + h], acc[o]);
        }
#pragma unroll
        for (int h = 0; h < 32; ++h) {
            const float bit = (float)((mm.y >> h) & 1u);
#pragma unroll
            for (int o = 0; o < OUT_SZ; ++o)
                acc[o] = fmaf(bit, W2[o * H_SZ + 32 + h], acc[o]);
        }
#pragma unroll
        for (int h = 0; h < 32; ++h) {
            const float bit = (float)((mm.z >> h) & 1u);
#pragma unroll
            for (int o = 0; o < OUT_SZ; ++o)
                acc[o] = fmaf(bit, W2[o * H_SZ + 64 + h], acc[o]);
        }
#pragma unroll
        for (int h = 0; h < 32; ++h) {
            const float bit = (float)((mm.w >> h) & 1u);
#pragma unroll
            for (int o = 0; o < OUT_SZ; ++o)
                acc[o] = fmaf(bit, W2[o * H_SZ + 96 + h], acc[o]);
        }

#pragma unroll
        for (int o = 0; o < OUT_SZ; ++o)
            c2[t * OUT_SZ + o] = acc[o] + b2[o];
    }
    __syncthreads();

    // =========== phase 3: mem2 scan, lanes 0..8 (chunked, burst stores) ===========
    if (tid < OUT_SZ) {
        const int o = tid;
        const float bt2 = fminf(fmaxf(beta2p[0], 0.0f), 1.0f);
        const float th2 = thr2p[0];

        float* __restrict__ out_spk = out + (size_t)b * OUT_SZ + o;
        float* __restrict__ out_mem = out + (size_t)T_STEPS * NBO + (size_t)b * OUT_SZ + o;

        float mem2 = 0.0f;

        float A[16], Bb[16];
#pragma unroll
        for (int j = 0; j < 16; ++j) A[j]  = c2[j * OUT_SZ + o];
#pragma unroll
        for (int j = 0; j < 16; ++j) Bb[j] = c2[(16 + j) * OUT_SZ + o];

        float sE[16], mE[16], sO[16], mO[16];

        for (int c = 0; c < NCHUNK; c += 2) {
            // even chunk c
#pragma unroll
            for (int j = 0; j < 16; ++j) {
                mem2 = fmaf(bt2, mem2, A[j]);
                const float sp = (mem2 > th2) ? 1.0f : 0.0f;
                mem2 = fmaf(-sp, th2, mem2);
                sE[j] = sp; mE[j] = mem2;
            }
            const int cn = (c + 2 < NCHUNK) ? (c + 2) : c;
#pragma unroll
            for (int j = 0; j < 16; ++j) A[j] = c2[(cn * 16 + j) * OUT_SZ + o];
            {
                const size_t base = (size_t)c * 16 * NBO;
#pragma unroll
                for (int j = 0; j < 16; ++j) {
                    out_spk[base + (size_t)j * NBO] = sE[j];
                    out_mem[base + (size_t)j * NBO] = mE[j];
                }
            }

            // odd chunk c+1
#pragma unroll
            for (int j = 0; j < 16; ++j) {
                mem2 = fmaf(bt2, mem2, Bb[j]);
                const float sp = (mem2 > th2) ? 1.0f : 0.0f;
                mem2 = fmaf(-sp, th2, mem2);
                sO[j] = sp; mO[j] = mem2;
            }
            const int cn2 = (c + 3 < NCHUNK) ? (c + 3) : c;
#pragma unroll
            for (int j = 0; j < 16; ++j) Bb[j] = c2[(cn2 * 16 + j) * OUT_SZ + o];
            if (c + 1 < NCHUNK - 1) {
                const size_t base = (size_t)(c + 1) * 16 * NBO;
#pragma unroll
                for (int j = 0; j < 16; ++j) {
                    out_spk[base + (size_t)j * NBO] = sO[j];
                    out_mem[base + (size_t)j * NBO] = mO[j];
                }
            } else {
                // last chunk: t = 336..351 -> store only t < 345
                const size_t base = (size_t)(c + 1) * 16 * NBO;
#pragma unroll
                for (int j = 0; j < 9; ++j) {
                    out_spk[base + (size_t)j * NBO] = sO[j];
                    out_mem[base + (size_t)j * NBO] = mO[j];
                }
            }
        }
    }
}

extern "C" void kernel_launch(void* const* d_in, const int* in_sizes, int n_in,
                              void* d_out, int out_size, void* d_ws, size_t ws_size,
                              hipStream_t stream) {
    const float* x     = (const float*)d_in[0];
    const float* W1    = (const float*)d_in[1];
    const float* b1    = (const float*)d_in[2];
    const float* W2    = (const float*)d_in[3];
    const float* b2    = (const float*)d_in[4];
    const float* beta1 = (const float*)d_in[5];
    const float* thr1  = (const float*)d_in[6];
    const float* beta2 = (const float*)d_in[7];
    const float* thr2  = (const float*)d_in[8];
    float* out = (float*)d_out;

    snn_fused<<<dim3(B_SZ), dim3(384), 0, stream>>>(
        x, W1, b1, W2, b2, beta1, thr1, beta2, thr2, out);
}